// Round 3
// baseline (620.844 us; speedup 1.0000x reference)
//
#include <hip/hip_runtime.h>
#include <cstdint>

#define B_   16
#define CIN  128
#define COUT 128
#define SD   512
#define H_   128
#define W_   128

typedef __bf16 bf16x8  __attribute__((ext_vector_type(8)));
typedef float  floatx4 __attribute__((ext_vector_type(4)));
typedef float floatx16 __attribute__((ext_vector_type(16)));

// ---------- kernel A: style[b][c] = (sv[b]/sqrt(512)) . proj_w[c] + proj_b[c]
__global__ void style_kernel(const float* __restrict__ sv, const float* __restrict__ pw,
                             const float* __restrict__ pb, float* __restrict__ style) {
    int bid = blockIdx.x;
    int b = bid >> 7, c = bid & 127;
    int lane = threadIdx.x;
    const float* svb = sv + b * SD;
    const float* pwc = pw + (size_t)c * SD;
    float s = 0.f;
#pragma unroll
    for (int i = 0; i < SD; i += 64) s += svb[i + lane] * pwc[i + lane];
#pragma unroll
    for (int off = 32; off > 0; off >>= 1) s += __shfl_down(s, off, 64);
    if (lane == 0) style[b * CIN + c] = s * 0.044194173824159216f + pb[c];
}

// ---------- kernel B: modulate + demod, emit bf16 in [b][tap][chunk][o][c16] layout
__global__ void modw_kernel(const float* __restrict__ weight, const float* __restrict__ style,
                            __bf16* __restrict__ wmod) {
    int bid = blockIdx.x;
    int b = bid >> 7, o = bid & 127;
    int c = threadIdx.x;  // 0..127
    float s = style[b * CIN + c];
    const float* wp = weight + ((size_t)o * CIN + c) * 9;
    float v[9];
    float ss = 0.f;
#pragma unroll
    for (int t = 0; t < 9; ++t) { v[t] = wp[t] * s; ss += v[t] * v[t]; }
#pragma unroll
    for (int off = 32; off > 0; off >>= 1) ss += __shfl_down(ss, off, 64);
    __shared__ float sh[2];
    int wid = c >> 6, lane = c & 63;
    if (lane == 0) sh[wid] = ss;
    __syncthreads();
    float d = rsqrtf(sh[0] + sh[1] + 1e-8f);
    int chunk = c >> 4, ci = c & 15;
#pragma unroll
    for (int t = 0; t < 9; ++t) {
        wmod[(((((size_t)b * 9 + t) * 8 + chunk) * 128 + o) * 16 + ci)] = (__bf16)(v[t] * d);
    }
}

// ---------- kernel C: fused transpose + implicit-GEMM conv (v2)
// block = 512 threads (8 waves), output tile: 128 o x 4 rows x 64 w.
// 6 input rows staged (halo 1.5x, vs 2x that sank v1). K chunked 8 x 16c with the
// ROUND-1-PROVEN pipeline: per chunk {hoist 18 A b128 -> ds_write staged regs ->
// prefetch next chunk staging -> lgkmcnt(0)+raw barrier (A stays in flight) ->
// 9 taps x 2 wt ds_read_b128 + 36 MFMA}. Staging gathers 8-channel granules from
// fp32 x (8 wave-coalesced dword loads per granule) and writes ONE contiguous
// b128 per slot -> conflict-free LDS writes, read layout identical to round-1.
#define WXT 66
__global__ __launch_bounds__(512, 4)
void conv_kernel(const float* __restrict__ x, const __bf16* __restrict__ wmod,
                 float* __restrict__ out) {
    __shared__ __align__(16) __bf16 Xs[2][6 * WXT * 16];  // 2 x 12672 B
    int w0 = blockIdx.x * 64;
    int h0 = blockIdx.y * 4;
    int b  = blockIdx.z;
    int tid = threadIdx.x;
    int wv = tid >> 6, lane = tid & 63;
    int n = lane & 31, hf = lane >> 5;
    int obase = (wv & 1) * 64;
    int r = wv >> 1;              // output row 0..3

    floatx16 acc[2][2];
#pragma unroll
    for (int i = 0; i < 2; ++i)
#pragma unroll
        for (int j = 0; j < 2; ++j)
#pragma unroll
            for (int k = 0; k < 16; ++k) acc[i][j][k] = 0.f;

    // staging slots: 792 granules = 6 rows x 66 wp x 2 c-halves; slot = (rr,wp,hfs)
    // granule g holds channels {ch*16 + hfs*8 + 0..7} at (hh, ww), written to
    // LDS elem offset g*8 (contiguous b128 per slot -> bank-conflict-free).
    bool sact[2], sval[2];
    const float* sp[2];
    int soff[2];
#pragma unroll
    for (int s = 0; s < 2; ++s) {
        int idx = tid + s * 512;
        bool act = (s == 0) || (tid < 280);
        int rr = idx / 132;
        int rem = idx - rr * 132;
        int wp = rem >> 1, hfs = rem & 1;
        int hh = h0 - 1 + rr, ww = w0 - 1 + wp;
        bool ok = act && (unsigned)hh < (unsigned)H_ && (unsigned)ww < (unsigned)W_;
        sact[s] = act;
        sval[s] = ok;
        sp[s] = x + (((size_t)b * CIN + hfs * 8) * H_ + (ok ? hh : 0)) * W_ + (ok ? ww : 0);
        soff[s] = idx * 8;
    }

    // staging registers: raw f32, packed to bf16 at write time (next iter, after
    // the compiler's counted vmcnt that leaves this chunk's A-loads in flight)
    float sv2[2][8];
#pragma unroll
    for (int s = 0; s < 2; ++s)
#pragma unroll
        for (int j = 0; j < 8; ++j)
            sv2[s][j] = sval[s] ? sp[s][(size_t)j * (H_ * W_)] : 0.f;   // chunk 0

    const __bf16* apb = wmod + (size_t)b * 147456 + ((size_t)obase + n) * 16 + hf * 8;
    // wmod strides (elems): tap 16384, chunk 2048, o+32 512

    for (int ch = 0; ch < 8; ++ch) {
        // 1) hoist A-fragment loads for this chunk (18 b128, stay in flight)
        bf16x8 a[9][2];
#pragma unroll
        for (int tap = 0; tap < 9; ++tap) {
            const __bf16* ap = apb + tap * 16384 + ch * 2048;
            a[tap][0] = *(const bf16x8*)ap;
            a[tap][1] = *(const bf16x8*)(ap + 512);
        }
        // 2) pack + write prefetched staging regs to this chunk's LDS buffer
        //    (vmcnt here counts only the 18 A-loads above -> staging drained, A not)
        __bf16* xbuf = &Xs[ch & 1][0];
#pragma unroll
        for (int s = 0; s < 2; ++s) {
            if (sact[s]) {
                uint4 pk;
                uint32_t wds[4];
#pragma unroll
                for (int p = 0; p < 4; ++p) {
                    uint32_t lo = (uint32_t)__builtin_bit_cast(unsigned short, (__bf16)sv2[s][2 * p]);
                    uint32_t hi = (uint32_t)__builtin_bit_cast(unsigned short, (__bf16)sv2[s][2 * p + 1]);
                    wds[p] = lo | (hi << 16);
                }
                pk.x = wds[0]; pk.y = wds[1]; pk.z = wds[2]; pk.w = wds[3];
                *(uint4*)(xbuf + soff[s]) = pk;
            }
        }
        // 3) prefetch next chunk's staging into regs (issued after A -> newer)
        if (ch < 7) {
#pragma unroll
            for (int s = 0; s < 2; ++s)
#pragma unroll
                for (int j = 0; j < 8; ++j)
                    sv2[s][j] = sval[s] ? sp[s][((size_t)(ch + 1) * 16 + j) * (H_ * W_)] : 0.f;
        }
        // 4) LDS fence + raw barrier; A-loads/prefetch stay in flight (counted
        //    vmcnt at first use). Dbuf invariant identical to round-1.
        asm volatile("s_waitcnt lgkmcnt(0)" ::: "memory");
        __builtin_amdgcn_s_barrier();
        asm volatile("" ::: "memory");  // keep ds_reads below the barrier
        // 5) compute: pure LDS reads + MFMA, A from registers
#pragma unroll
        for (int tap = 0; tap < 9; ++tap) {
            int kh = tap / 3, kw = tap % 3;
            int row = r + kh;             // 0..5
#pragma unroll
            for (int wt = 0; wt < 2; ++wt) {
                int wp = wt * 32 + n + kw;
                bf16x8 bfrag = *(const bf16x8*)(xbuf + (row * WXT + wp) * 16 + hf * 8);
                acc[0][wt] = __builtin_amdgcn_mfma_f32_32x32x16_bf16(a[tap][0], bfrag, acc[0][wt], 0, 0, 0);
                acc[1][wt] = __builtin_amdgcn_mfma_f32_32x32x16_bf16(a[tap][1], bfrag, acc[1][wt], 0, 0, 0);
            }
        }
    }

    // epilogue: C/D layout col=lane&31, row=(reg&3)+8*(reg>>2)+4*(lane>>5)
    float* ob = out + (((size_t)b * COUT) * H_ + (h0 + r)) * W_ + w0;
#pragma unroll
    for (int i = 0; i < 2; ++i) {
#pragma unroll
        for (int reg = 0; reg < 16; ++reg) {
            int o = obase + i * 32 + (reg & 3) + 8 * (reg >> 2) + 4 * hf;
#pragma unroll
            for (int wt = 0; wt < 2; ++wt)
                __builtin_nontemporal_store(acc[i][wt][reg],
                    &ob[(size_t)o * (H_ * W_) + wt * 32 + n]);
        }
    }
}

extern "C" void kernel_launch(void* const* d_in, const int* in_sizes, int n_in,
                              void* d_out, int out_size, void* d_ws, size_t ws_size,
                              hipStream_t stream) {
    const float* x      = (const float*)d_in[0];
    const float* sv     = (const float*)d_in[1];
    const float* pw     = (const float*)d_in[2];
    const float* pb     = (const float*)d_in[3];
    const float* weight = (const float*)d_in[4];
    float* out = (float*)d_out;

    float*  style = (float*)d_ws;                            // 8 KB
    __bf16* wmod  = (__bf16*)((char*)d_ws + 8192);           // 4.72 MB

    style_kernel<<<B_ * CIN, 64, 0, stream>>>(sv, pw, pb, style);
    modw_kernel<<<B_ * COUT, 128, 0, stream>>>(weight, style, wmod);
    conv_kernel<<<dim3(2, 32, B_), 512, 0, stream>>>(x, wmod, out);
}

// Round 4
// 304.867 us; speedup vs baseline: 2.0364x; 2.0364x over previous
//
#include <hip/hip_runtime.h>
#include <cstdint>

#define B_   16
#define CIN  128
#define COUT 128
#define SD   512
#define H_   128
#define W_   128

typedef __bf16 bf16x8  __attribute__((ext_vector_type(8)));
typedef float  floatx4 __attribute__((ext_vector_type(4)));
typedef float floatx16 __attribute__((ext_vector_type(16)));

// ---------- kernel A: style[b][c] = (sv[b]/sqrt(512)) . proj_w[c] + proj_b[c]
__global__ void style_kernel(const float* __restrict__ sv, const float* __restrict__ pw,
                             const float* __restrict__ pb, float* __restrict__ style) {
    int bid = blockIdx.x;
    int b = bid >> 7, c = bid & 127;
    int lane = threadIdx.x;
    const float* svb = sv + b * SD;
    const float* pwc = pw + (size_t)c * SD;
    float s = 0.f;
#pragma unroll
    for (int i = 0; i < SD; i += 64) s += svb[i + lane] * pwc[i + lane];
#pragma unroll
    for (int off = 32; off > 0; off >>= 1) s += __shfl_down(s, off, 64);
    if (lane == 0) style[b * CIN + c] = s * 0.044194173824159216f + pb[c];
}

// ---------- kernel B: modulate + demod, emit bf16 in [b][tap][chunk][o][c16] layout
__global__ void modw_kernel(const float* __restrict__ weight, const float* __restrict__ style,
                            __bf16* __restrict__ wmod) {
    int bid = blockIdx.x;
    int b = bid >> 7, o = bid & 127;
    int c = threadIdx.x;  // 0..127
    float s = style[b * CIN + c];
    const float* wp = weight + ((size_t)o * CIN + c) * 9;
    float v[9];
    float ss = 0.f;
#pragma unroll
    for (int t = 0; t < 9; ++t) { v[t] = wp[t] * s; ss += v[t] * v[t]; }
#pragma unroll
    for (int off = 32; off > 0; off >>= 1) ss += __shfl_down(ss, off, 64);
    __shared__ float sh[2];
    int wid = c >> 6, lane = c & 63;
    if (lane == 0) sh[wid] = ss;
    __syncthreads();
    float d = rsqrtf(sh[0] + sh[1] + 1e-8f);
    int chunk = c >> 4, ci = c & 15;
#pragma unroll
    for (int t = 0; t < 9; ++t) {
        wmod[(((((size_t)b * 9 + t) * 8 + chunk) * 128 + o) * 16 + ci)] = (__bf16)(v[t] * d);
    }
}

// ---------- kernel C: fused transpose + implicit-GEMM conv (v2-fixed)
// IDENTICAL to the round-2 kernel (correctness-verified) except launch_bounds:
// (512,4) clamped VGPR to 64 -> acc/A-frag/staging spilled to scratch
// (~600 MB spill writes per dispatch, WRITE_SIZE 738 MB, conv 467 us).
// (512,2) caps at 256 VGPR -> no spills, 1 block/CU = 8 waves/CU (same
// resident-wave count as the round-1 2-blocks x 4-waves config).
//
// block = 512 threads (8 waves), output tile: 128 o x 4 rows x 64 w.
// 6 input rows staged (halo 1.5x). K chunked 8 x 16c with the round-1-proven
// pipeline: per chunk {hoist 18 A b128 -> ds_write staged regs -> prefetch next
// chunk staging -> lgkmcnt(0)+raw barrier (A stays in flight) -> 18 ds_read_b128
// + 36 MFMA}.
#define WXT 66
__global__ __launch_bounds__(512, 2)
void conv_kernel(const float* __restrict__ x, const __bf16* __restrict__ wmod,
                 float* __restrict__ out) {
    __shared__ __align__(16) __bf16 Xs[2][6 * WXT * 16];  // 2 x 12672 B
    int w0 = blockIdx.x * 64;
    int h0 = blockIdx.y * 4;
    int b  = blockIdx.z;
    int tid = threadIdx.x;
    int wv = tid >> 6, lane = tid & 63;
    int n = lane & 31, hf = lane >> 5;
    int obase = (wv & 1) * 64;
    int r = wv >> 1;              // output row 0..3

    floatx16 acc[2][2];
#pragma unroll
    for (int i = 0; i < 2; ++i)
#pragma unroll
        for (int j = 0; j < 2; ++j)
#pragma unroll
            for (int k = 0; k < 16; ++k) acc[i][j][k] = 0.f;

    // staging slots: 792 granules = 6 rows x 66 wp x 2 c-halves; slot = (rr,wp,hfs)
    // granule g holds channels {ch*16 + hfs*8 + 0..7} at (hh, ww), written to
    // LDS elem offset g*8 (contiguous b128 per slot -> bank-conflict-free).
    bool sact[2], sval[2];
    const float* sp[2];
    int soff[2];
#pragma unroll
    for (int s = 0; s < 2; ++s) {
        int idx = tid + s * 512;
        bool act = (s == 0) || (tid < 280);
        int rr = idx / 132;
        int rem = idx - rr * 132;
        int wp = rem >> 1, hfs = rem & 1;
        int hh = h0 - 1 + rr, ww = w0 - 1 + wp;
        bool ok = act && (unsigned)hh < (unsigned)H_ && (unsigned)ww < (unsigned)W_;
        sact[s] = act;
        sval[s] = ok;
        sp[s] = x + (((size_t)b * CIN + hfs * 8) * H_ + (ok ? hh : 0)) * W_ + (ok ? ww : 0);
        soff[s] = idx * 8;
    }

    // staging registers: raw f32, packed to bf16 at write time (next iter, after
    // the compiler's counted vmcnt that leaves this chunk's A-loads in flight)
    float sv2[2][8];
#pragma unroll
    for (int s = 0; s < 2; ++s)
#pragma unroll
        for (int j = 0; j < 8; ++j)
            sv2[s][j] = sval[s] ? sp[s][(size_t)j * (H_ * W_)] : 0.f;   // chunk 0

    const __bf16* apb = wmod + (size_t)b * 147456 + ((size_t)obase + n) * 16 + hf * 8;
    // wmod strides (elems): tap 16384, chunk 2048, o+32 512

    for (int ch = 0; ch < 8; ++ch) {
        // 1) hoist A-fragment loads for this chunk (18 b128, stay in flight)
        bf16x8 a[9][2];
#pragma unroll
        for (int tap = 0; tap < 9; ++tap) {
            const __bf16* ap = apb + tap * 16384 + ch * 2048;
            a[tap][0] = *(const bf16x8*)ap;
            a[tap][1] = *(const bf16x8*)(ap + 512);
        }
        // 2) pack + write prefetched staging regs to this chunk's LDS buffer
        __bf16* xbuf = &Xs[ch & 1][0];
#pragma unroll
        for (int s = 0; s < 2; ++s) {
            if (sact[s]) {
                uint4 pk;
                uint32_t wds[4];
#pragma unroll
                for (int p = 0; p < 4; ++p) {
                    uint32_t lo = (uint32_t)__builtin_bit_cast(unsigned short, (__bf16)sv2[s][2 * p]);
                    uint32_t hi = (uint32_t)__builtin_bit_cast(unsigned short, (__bf16)sv2[s][2 * p + 1]);
                    wds[p] = lo | (hi << 16);
                }
                pk.x = wds[0]; pk.y = wds[1]; pk.z = wds[2]; pk.w = wds[3];
                *(uint4*)(xbuf + soff[s]) = pk;
            }
        }
        // 3) prefetch next chunk's staging into regs (issued after A -> newer)
        if (ch < 7) {
#pragma unroll
            for (int s = 0; s < 2; ++s)
#pragma unroll
                for (int j = 0; j < 8; ++j)
                    sv2[s][j] = sval[s] ? sp[s][((size_t)(ch + 1) * 16 + j) * (H_ * W_)] : 0.f;
        }
        // 4) LDS fence + raw barrier; A-loads/prefetch stay in flight (counted
        //    vmcnt at first use). Dbuf invariant identical to round-1.
        asm volatile("s_waitcnt lgkmcnt(0)" ::: "memory");
        __builtin_amdgcn_s_barrier();
        asm volatile("" ::: "memory");  // keep ds_reads below the barrier
        // 5) compute: pure LDS reads + MFMA, A from registers
#pragma unroll
        for (int tap = 0; tap < 9; ++tap) {
            int kh = tap / 3, kw = tap % 3;
            int row = r + kh;             // 0..5
#pragma unroll
            for (int wt = 0; wt < 2; ++wt) {
                int wp = wt * 32 + n + kw;
                bf16x8 bfrag = *(const bf16x8*)(xbuf + (row * WXT + wp) * 16 + hf * 8);
                acc[0][wt] = __builtin_amdgcn_mfma_f32_32x32x16_bf16(a[tap][0], bfrag, acc[0][wt], 0, 0, 0);
                acc[1][wt] = __builtin_amdgcn_mfma_f32_32x32x16_bf16(a[tap][1], bfrag, acc[1][wt], 0, 0, 0);
            }
        }
    }

    // epilogue: C/D layout col=lane&31, row=(reg&3)+8*(reg>>2)+4*(lane>>5)
    float* ob = out + (((size_t)b * COUT) * H_ + (h0 + r)) * W_ + w0;
#pragma unroll
    for (int i = 0; i < 2; ++i) {
#pragma unroll
        for (int reg = 0; reg < 16; ++reg) {
            int o = obase + i * 32 + (reg & 3) + 8 * (reg >> 2) + 4 * hf;
#pragma unroll
            for (int wt = 0; wt < 2; ++wt)
                __builtin_nontemporal_store(acc[i][wt][reg],
                    &ob[(size_t)o * (H_ * W_) + wt * 32 + n]);
        }
    }
}

extern "C" void kernel_launch(void* const* d_in, const int* in_sizes, int n_in,
                              void* d_out, int out_size, void* d_ws, size_t ws_size,
                              hipStream_t stream) {
    const float* x      = (const float*)d_in[0];
    const float* sv     = (const float*)d_in[1];
    const float* pw     = (const float*)d_in[2];
    const float* pb     = (const float*)d_in[3];
    const float* weight = (const float*)d_in[4];
    float* out = (float*)d_out;

    float*  style = (float*)d_ws;                            // 8 KB
    __bf16* wmod  = (__bf16*)((char*)d_ws + 8192);           // 4.72 MB

    style_kernel<<<B_ * CIN, 64, 0, stream>>>(sv, pw, pb, style);
    modw_kernel<<<B_ * COUT, 128, 0, stream>>>(weight, style, wmod);
    conv_kernel<<<dim3(2, 32, B_), 512, 0, stream>>>(x, wmod, out);
}